// Round 4
// baseline (485.765 us; speedup 1.0000x reference)
//
#include <hip/hip_runtime.h>
#include <hip/hip_fp16.h>

#define N_PIX 9216
#define CCH 256
#define W_ 96
#define H_ 96
#define BM 128
#define BN 128
#define BK 16
#define TM 8
#define TN 8

typedef _Float16 half8_t __attribute__((ext_vector_type(8)));
typedef float f32x4_t __attribute__((ext_vector_type(4)));

// Monotone encoding: unsigned compare order == float compare order.
__device__ __forceinline__ unsigned int mono_enc(float f) {
    unsigned int u = __float_as_uint(f);
    return (u & 0x80000000u) ? ~u : (u | 0x80000000u);
}
__device__ __forceinline__ float mono_dec(unsigned int e) {
    return __uint_as_float((e & 0x80000000u) ? (e ^ 0x80000000u) : ~e);
}

// async global->LDS, 16B per lane; LDS dest is wave-uniform base + lane*16.
__device__ __forceinline__ void gload_lds16(const uint4* g, uint4* lds) {
    __builtin_amdgcn_global_load_lds(
        (const __attribute__((address_space(1))) unsigned int*)g,
        (__attribute__((address_space(3))) unsigned int*)lds, 16, 0, 0);
}

// ======================= legacy (fallback) path =======================

__global__ __launch_bounds__(256) void norms_kernel(const float* __restrict__ Q,
                                                    const float* __restrict__ P,
                                                    float* __restrict__ invq,
                                                    float* __restrict__ invp) {
    int n = blockIdx.x * blockDim.x + threadIdx.x;
    if (n >= N_PIX) return;
    float sq = 0.f, sp = 0.f;
    for (int c = 0; c < CCH; ++c) {
        float a = Q[(size_t)c * N_PIX + n];
        float b = P[(size_t)c * N_PIX + n];
        sq = fmaf(a, a, sq);
        sp = fmaf(b, b, sp);
    }
    invq[n] = 1.0f / sqrtf(sq);
    invp[n] = 1.0f / sqrtf(sp);
}

__device__ __forceinline__ int local_row(int ty, int i) {
    return (i < 4) ? (ty * 4 + i) : (64 + ty * 4 + (i - 4));
}
__device__ __forceinline__ int local_col(int tx, int j) {
    return (j < 4) ? (tx * 4 + j) : (64 + tx * 4 + (j - 4));
}

__global__ __launch_bounds__(256) void gemm_kernel(const float* __restrict__ Q,
                                                   const float* __restrict__ P,
                                                   const float* __restrict__ invq,
                                                   const float* __restrict__ invp,
                                                   float* __restrict__ sim,
                                                   unsigned long long* __restrict__ row_best,
                                                   unsigned long long* __restrict__ col_best) {
    __shared__ union SH {
        struct { float A[BK][BM]; float B[BK][BN]; } t;
        unsigned long long red[16][128];
    } sh;

    const int tid = threadIdx.x;
    const int tx = tid & 15;
    const int ty = tid >> 4;
    const int n0 = blockIdx.y * BM;
    const int m0 = blockIdx.x * BN;

    float acc[TM][TN];
#pragma unroll
    for (int i = 0; i < TM; ++i)
#pragma unroll
        for (int j = 0; j < TN; ++j) acc[i][j] = 0.f;

    for (int kk = 0; kk < CCH; kk += BK) {
#pragma unroll
        for (int rep = 0; rep < 2; ++rep) {
            int idx = tid + rep * 256;
            int row = idx >> 5;
            int c4  = idx & 31;
            float4 av = *(const float4*)&Q[(size_t)(kk + row) * N_PIX + n0 + c4 * 4];
            float4 bv = *(const float4*)&P[(size_t)(kk + row) * N_PIX + m0 + c4 * 4];
            *(float4*)&sh.t.A[row][c4 * 4] = av;
            *(float4*)&sh.t.B[row][c4 * 4] = bv;
        }
        __syncthreads();
#pragma unroll
        for (int k = 0; k < BK; ++k) {
            float a[TM], b[TN];
            *(float4*)&a[0] = *(const float4*)&sh.t.A[k][ty * 4];
            *(float4*)&a[4] = *(const float4*)&sh.t.A[k][ty * 4 + 64];
            *(float4*)&b[0] = *(const float4*)&sh.t.B[k][tx * 4];
            *(float4*)&b[4] = *(const float4*)&sh.t.B[k][tx * 4 + 64];
#pragma unroll
            for (int i = 0; i < TM; ++i)
#pragma unroll
                for (int j = 0; j < TN; ++j)
                    acc[i][j] = fmaf(a[i], b[j], acc[i][j]);
        }
        __syncthreads();
    }

    float iq[TM], ip[TN];
#pragma unroll
    for (int i = 0; i < TM; ++i) iq[i] = invq[n0 + local_row(ty, i)];
#pragma unroll
    for (int j = 0; j < TN; ++j) ip[j] = invp[m0 + local_col(tx, j)];
#pragma unroll
    for (int i = 0; i < TM; ++i)
#pragma unroll
        for (int j = 0; j < TN; ++j) acc[i][j] *= iq[i] * ip[j];

#pragma unroll
    for (int i = 0; i < TM; ++i) {
        int n = n0 + local_row(ty, i);
        float4 v0 = make_float4(acc[i][0], acc[i][1], acc[i][2], acc[i][3]);
        float4 v1 = make_float4(acc[i][4], acc[i][5], acc[i][6], acc[i][7]);
        float* dst = &sim[(size_t)n * N_PIX + m0];
        *(float4*)(dst + tx * 4) = v0;
        *(float4*)(dst + 64 + tx * 4) = v1;
    }

#pragma unroll
    for (int i = 0; i < TM; ++i) {
        float best = acc[i][0]; int bj = 0;
#pragma unroll
        for (int j = 1; j < TN; ++j)
            if (acc[i][j] > best) { best = acc[i][j]; bj = j; }
        unsigned int gcol = (unsigned int)(m0 + local_col(tx, bj));
        sh.red[tx][local_row(ty, i)] =
            ((unsigned long long)mono_enc(best) << 32) | (unsigned long long)(0xFFFFFFFFu - gcol);
    }
    __syncthreads();
    if (tid < 128) {
        unsigned long long best = sh.red[0][tid];
#pragma unroll
        for (int x = 1; x < 16; ++x) {
            unsigned long long v = sh.red[x][tid];
            if (v > best) best = v;
        }
        atomicMax(&row_best[n0 + tid], best);
    }
    __syncthreads();

#pragma unroll
    for (int j = 0; j < TN; ++j) {
        float best = acc[0][j]; int bi = 0;
#pragma unroll
        for (int i = 1; i < TM; ++i)
            if (acc[i][j] > best) { best = acc[i][j]; bi = i; }
        unsigned int grow = (unsigned int)(n0 + local_row(ty, bi));
        sh.red[ty][local_col(tx, j)] =
            ((unsigned long long)mono_enc(best) << 32) | (unsigned long long)(0xFFFFFFFFu - grow);
    }
    __syncthreads();
    if (tid < 128) {
        unsigned long long best = sh.red[0][tid];
#pragma unroll
        for (int x = 1; x < 16; ++x) {
            unsigned long long v = sh.red[x][tid];
            if (v > best) best = v;
        }
        atomicMax(&col_best[m0 + tid], best);
    }
}

// ======================= fast (MFMA) path =======================

__device__ __forceinline__ unsigned int pack_pair(float x, float y, float& rx, float& ry) {
    __half hx = __float2half(x), hy = __float2half(y);
    rx = x - __half2float(hx);
    ry = y - __half2float(hy);
    return (unsigned int)__half_as_ushort(hx) | ((unsigned int)__half_as_ushort(hy) << 16);
}

// Fused norms + fp16-split kernel. Output layout is FRAGMENT-MAJOR:
// for kb = dword-row/4 (0..31), array[kb*N_PIX + n] is a uint4 holding the
// 4 k-pair dwords (k = kb*8 .. kb*8+7) of pixel n == exactly one MFMA
// fragment register group, loadable with a single (dwordx4 | lds_dwordx4).
__global__ __launch_bounds__(256) void prep_kernel(const float* __restrict__ Q,
                                                   const float* __restrict__ P,
                                                   uint4* __restrict__ qh,
                                                   uint4* __restrict__ ql,
                                                   uint4* __restrict__ ph,
                                                   uint4* __restrict__ pl,
                                                   float* __restrict__ invq,
                                                   float* __restrict__ invp) {
    __shared__ float rq[4][64];
    __shared__ float rp[4][64];
    const int lane = threadIdx.x & 63;
    const int band = threadIdx.x >> 6;
    const int n = blockIdx.x * 64 + lane;
    float sq = 0.f, sp = 0.f;
    for (int kb = band * 8; kb < band * 8 + 8; ++kb) {
        float a[8], b[8];
#pragma unroll
        for (int t = 0; t < 8; ++t) {
            a[t] = Q[(size_t)(kb * 8 + t) * N_PIX + n];
            b[t] = P[(size_t)(kb * 8 + t) * N_PIX + n];
        }
#pragma unroll
        for (int t = 0; t < 8; ++t) {
            sq = fmaf(a[t], a[t], sq);
            sp = fmaf(b[t], b[t], sp);
        }
        uint4 vqh, vql, vph, vpl;
        unsigned int* uqh = (unsigned int*)&vqh;
        unsigned int* uql = (unsigned int*)&vql;
        unsigned int* uph = (unsigned int*)&vph;
        unsigned int* upl = (unsigned int*)&vpl;
#pragma unroll
        for (int j = 0; j < 4; ++j) {
            float r0, r1;
            uqh[j] = pack_pair(a[2 * j], a[2 * j + 1], r0, r1);
            uql[j] = (unsigned int)__half_as_ushort(__float2half(r0))
                   | ((unsigned int)__half_as_ushort(__float2half(r1)) << 16);
            uph[j] = pack_pair(b[2 * j], b[2 * j + 1], r0, r1);
            upl[j] = (unsigned int)__half_as_ushort(__float2half(r0))
                   | ((unsigned int)__half_as_ushort(__float2half(r1)) << 16);
        }
        size_t o = (size_t)kb * N_PIX + n;
        qh[o] = vqh; ql[o] = vql; ph[o] = vph; pl[o] = vpl;
    }
    rq[band][lane] = sq;
    rp[band][lane] = sp;
    __syncthreads();
    if (threadIdx.x < 64) {
        float tq = rq[0][lane] + rq[1][lane] + rq[2][lane] + rq[3][lane];
        float tp = rp[0][lane] + rp[1][lane] + rp[2][lane] + rp[3][lane];
        invq[n] = 1.0f / sqrtf(tq);
        invp[n] = 1.0f / sqrtf(tp);
    }
}

// 192x192 tile, 8 waves (512 thr), wave = 48 rows x 96 cols = 3x6 fragments
// of 16x16x32 f16 MFMA, 3-term fp16 split (hi*hi + hi*lo + lo*hi).
// Grid 48x48 = 2304 blocks = exactly 9 rounds of 256 CUs (zero tail).
// K-loop: TRIPLE-buffered LDS (3 x 48 KB), prefetch depth 2, raw s_barrier
// with COUNTED vmcnt(6) -> staging loads stay in flight across barriers
// (never drain to 0 in the main loop).
__global__ __launch_bounds__(512, 2) void mfma_gemm_kernel(
        const uint4* __restrict__ QH, const uint4* __restrict__ QL,
        const uint4* __restrict__ PH, const uint4* __restrict__ PL,
        const float* __restrict__ invq, const float* __restrict__ invp,
        float* __restrict__ sim,
        unsigned long long* __restrict__ row_best,
        unsigned long long* __restrict__ col_best) {
    // XCD swizzle: xcd = bid&7; each XCD owns 6 by-rows x 48 bx, walked in
    // 8-wide bx groups (resident set ~2.4 MB -> L2-fits per XCD).
    const unsigned int bid = blockIdx.x;
    const unsigned int xcd = bid & 7u;
    const unsigned int nbl = bid >> 3;          // 0..287
    const unsigned int g   = nbl >> 3;          // 0..35
    const unsigned int ii  = nbl & 7u;          // 0..7
    const unsigned int by  = xcd * 6u + g % 6u;     // 0..47
    const unsigned int bx  = (g / 6u) * 8u + ii;    // 0..47

    const int tid = threadIdx.x;
    const int l  = tid & 63;
    const int w  = tid >> 6;   // 0..7
    const int rl = l & 15;     // fragment row (A) / col (B,D)
    const int kg = l >> 4;     // k-group; also D-row group
    const int wr = w >> 1;     // 0..3 wave-row
    const int wc = w & 1;      // 0..1 wave-col
    const int n0 = (int)by * 192;
    const int m0 = (int)bx * 192;
    const int r0 = n0 + wr * 48;   // wave row base
    const int c0 = m0 + wc * 96;   // wave col base

    // stage: [3 bufs][arr Ah,Al,Bh,Bl][kb 0..3][pixel 0..191] = 144 KB,
    // union'd with the per-wave store-transpose buffer (used after the loop).
    __shared__ union SH2 {
        uint4 stage[3][4][4][192];
        float st[8][16][108];   // stride 108: 4-row offsets hit banks {0,16} -> 2-way (free)
    } sh;

    const f32x4_t zero4 = {0.f, 0.f, 0.f, 0.f};
    f32x4_t acc[3][6];
#pragma unroll
    for (int i = 0; i < 3; ++i)
#pragma unroll
        for (int j = 0; j < 6; ++j) acc[i][j] = zero4;

    // Stage assignment: chunk c = i*8+w -> arr = w&3 (wave-constant!),
    // rest = 2i + (w>>2) -> kb = rest&3, px0 = (rest>>2)*64. 6 chunks/wave.
    const int h3  = w >> 2;
    const int arr = w & 3;
    const uint4* gsrc = (arr == 0) ? (QH + n0) : (arr == 1) ? (QL + n0)
                      : (arr == 2) ? (PH + m0) : (PL + m0);

#define STAGE(step, buf)                                                        \
    {                                                                           \
        _Pragma("unroll")                                                       \
        for (int i = 0; i < 6; ++i) {                                           \
            const int rest = 2 * i + h3;                                        \
            const int kb = rest & 3;                                            \
            const int px0 = (rest >> 2) * 64;                                   \
            gload_lds16(gsrc + (size_t)((step) * 4 + kb) * N_PIX + px0 + l,     \
                        &sh.stage[buf][arr][kb][px0]);                          \
        }                                                                       \
    }

    // prologue: stage steps 0 and 1; wait step 0 (allow step 1's 6 in flight)
    STAGE(0, 0)
    STAGE(1, 1)
    asm volatile("s_waitcnt vmcnt(6)" ::: "memory");
    __builtin_amdgcn_s_barrier();
    __builtin_amdgcn_sched_barrier(0);

#pragma unroll
    for (int s = 0; s < 8; ++s) {
        const int cur = s % 3;
        if (s < 6) STAGE(s + 2, (s + 2) % 3)

        half8_t ah[3], al_[3], bh_[6], bl_[6];
#pragma unroll
        for (int f = 0; f < 3; ++f) {
            ah[f]  = *(const half8_t*)&sh.stage[cur][0][kg][wr * 48 + f * 16 + rl];
            al_[f] = *(const half8_t*)&sh.stage[cur][1][kg][wr * 48 + f * 16 + rl];
        }
#pragma unroll
        for (int f = 0; f < 6; ++f) {
            bh_[f] = *(const half8_t*)&sh.stage[cur][2][kg][wc * 96 + f * 16 + rl];
            bl_[f] = *(const half8_t*)&sh.stage[cur][3][kg][wc * 96 + f * 16 + rl];
        }
#pragma unroll
        for (int fr = 0; fr < 3; ++fr)
#pragma unroll
            for (int fc = 0; fc < 6; ++fc) {
                acc[fr][fc] = __builtin_amdgcn_mfma_f32_16x16x32_f16(ah[fr],  bh_[fc], acc[fr][fc], 0, 0, 0);
                acc[fr][fc] = __builtin_amdgcn_mfma_f32_16x16x32_f16(ah[fr],  bl_[fc], acc[fr][fc], 0, 0, 0);
                acc[fr][fc] = __builtin_amdgcn_mfma_f32_16x16x32_f16(al_[fr], bh_[fc], acc[fr][fc], 0, 0, 0);
            }

        if (s < 6) {
            asm volatile("s_waitcnt vmcnt(6)" ::: "memory");   // step s+1 landed; s+2 in flight
        } else if (s == 6) {
            asm volatile("s_waitcnt vmcnt(0)" ::: "memory");   // step 7 landed
        }
        __builtin_amdgcn_s_barrier();
        __builtin_amdgcn_sched_barrier(0);
    }
#undef STAGE

    // ---- scale by inverse norms (in-register) ----
    float iq[3][4];
#pragma unroll
    for (int fr = 0; fr < 3; ++fr) {
        const float4 v = *(const float4*)&invq[r0 + fr * 16 + kg * 4];
        iq[fr][0] = v.x; iq[fr][1] = v.y; iq[fr][2] = v.z; iq[fr][3] = v.w;
    }
    float ip[6];
#pragma unroll
    for (int fc = 0; fc < 6; ++fc) ip[fc] = invp[c0 + fc * 16 + rl];

#pragma unroll
    for (int fr = 0; fr < 3; ++fr)
#pragma unroll
        for (int fc = 0; fc < 6; ++fc)
#pragma unroll
            for (int j = 0; j < 4; ++j)
                acc[fr][fc][j] *= iq[fr][j] * ip[fc];

    // ---- row bests: reduce over this wave's 96 cols (fc in-lane, rl x-lane) ----
#pragma unroll
    for (int fr = 0; fr < 3; ++fr)
#pragma unroll
        for (int j = 0; j < 4; ++j) {
            float best = acc[fr][0][j];
            int bf = 0;
#pragma unroll
            for (int fc = 1; fc < 6; ++fc)
                if (acc[fr][fc][j] > best) { best = acc[fr][fc][j]; bf = fc; }
            const unsigned int gcol = (unsigned int)(c0 + bf * 16 + rl);
            unsigned long long key = ((unsigned long long)mono_enc(best) << 32)
                                   | (unsigned long long)(0xFFFFFFFFu - gcol);
#pragma unroll
            for (int m = 1; m < 16; m <<= 1) {
                unsigned long long o = __shfl_xor(key, m, 64);
                if (o > key) key = o;
            }
            if (rl == 0)
                atomicMax(&row_best[r0 + fr * 16 + kg * 4 + j], key);
        }

    // ---- col bests: reduce over this wave's 48 rows (fr,j in-lane, kg x-lane) ----
#pragma unroll
    for (int fc = 0; fc < 6; ++fc) {
        float best = acc[0][fc][0];
        unsigned int brow = (unsigned int)(r0 + kg * 4);
#pragma unroll
        for (int fr = 0; fr < 3; ++fr)
#pragma unroll
            for (int j = 0; j < 4; ++j) {
                float v = acc[fr][fc][j];  // rows scanned in increasing order
                unsigned int rr2 = (unsigned int)(r0 + fr * 16 + kg * 4 + j);
                if (v > best) { best = v; brow = rr2; }
            }
        unsigned long long key = ((unsigned long long)mono_enc(best) << 32)
                               | (unsigned long long)(0xFFFFFFFFu - brow);
#pragma unroll
        for (int m = 16; m < 64; m <<= 1) {
            unsigned long long o = __shfl_xor(key, m, 64);
            if (o > key) key = o;
        }
        if (kg == 0)
            atomicMax(&col_best[c0 + fc * 16 + rl], key);
    }

    // ---- sim stores via per-wave LDS transpose: full-line writes ----
    // (stage buffers are dead: final counted-wait + barrier ended the loop)
#pragma unroll
    for (int fr = 0; fr < 3; ++fr) {
        asm volatile("s_waitcnt lgkmcnt(0)" ::: "memory");  // prior fr's reads done
#pragma unroll
        for (int fc = 0; fc < 6; ++fc)
#pragma unroll
            for (int j = 0; j < 4; ++j)
                sh.st[w][kg * 4 + j][fc * 16 + rl] = acc[fr][fc][j];
        asm volatile("s_waitcnt lgkmcnt(0)" ::: "memory");  // writes visible to wave
#pragma unroll
        for (int p = 0; p < 6; ++p) {
            const int flat = p * 64 + l;
            const int row = flat / 24;       // 16 rows x 24 float4 = 384 slots
            const int c4  = flat % 24;
            const f32x4_t v = *(const f32x4_t*)&sh.st[w][row][c4 * 4];
            const int gr = r0 + fr * 16 + row;
            // 24 lanes x 16 B contiguous per row = 384 B aligned runs
            __builtin_nontemporal_store(v, (f32x4_t*)(sim + (size_t)gr * N_PIX + c0 + c4 * 4));
        }
    }
}

// ======================= shared epilogue =======================

__global__ __launch_bounds__(256) void epilogue_kernel(const unsigned long long* __restrict__ row_best,
                                                       const unsigned long long* __restrict__ col_best,
                                                       float* __restrict__ out) {
    int j = blockIdx.x * blockDim.x + threadIdx.x;
    if (j >= N_PIX) return;
    unsigned long long cb = col_best[j];
    unsigned int q_idx = 0xFFFFFFFFu - (unsigned int)(cb & 0xFFFFFFFFull);
    float simval = mono_dec((unsigned int)(cb >> 32));
    unsigned long long rb = row_best[q_idx];
    unsigned int rm = 0xFFFFFFFFu - (unsigned int)(rb & 0xFFFFFFFFull);
    bool mutual = (rm == (unsigned int)j) && (simval > 0.9f);
    int qd = (int)(q_idx / W_), qm = (int)(q_idx % W_);
    int pd = j / W_, pm = j % W_;
    bool valid = mutual && (qd + 1 < H_) && (pd + 1 < H_);
    size_t base = (size_t)N_PIX * N_PIX;
    out[base + 0 * (size_t)N_PIX + j] = valid ? 1.0f : 0.0f;
    out[base + 1 * (size_t)N_PIX + j] = (float)q_idx;
    out[base + 2 * (size_t)N_PIX + j] = (float)qd;
    out[base + 3 * (size_t)N_PIX + j] = (float)qm;
    out[base + 4 * (size_t)N_PIX + j] = (float)pd;
    out[base + 5 * (size_t)N_PIX + j] = (float)pm;
}

extern "C" void kernel_launch(void* const* d_in, const int* in_sizes, int n_in,
                              void* d_out, int out_size, void* d_ws, size_t ws_size,
                              hipStream_t stream) {
    const float* Q = (const float*)d_in[0];
    const float* P = (const float*)d_in[1];
    float* out = (float*)d_out;

    unsigned long long* row_best = (unsigned long long*)d_ws;
    unsigned long long* col_best = row_best + N_PIX;
    float* invq = (float*)(col_best + N_PIX);
    float* invp = invq + N_PIX;

    hipMemsetAsync(d_ws, 0, 2 * N_PIX * sizeof(unsigned long long), stream);

    const size_t base_bytes = 2 * N_PIX * sizeof(unsigned long long) + 2 * N_PIX * sizeof(float);
    const size_t arr_u4 = (size_t)(CCH / 8) * N_PIX;  // 32 kb-rows x N uint4
    const size_t need = base_bytes + 4 * arr_u4 * sizeof(uint4);

    if (ws_size >= need) {
        uint4* qh = (uint4*)((char*)d_ws + base_bytes);
        uint4* ql = qh + arr_u4;
        uint4* ph = ql + arr_u4;
        uint4* pl = ph + arr_u4;

        prep_kernel<<<N_PIX / 64, 256, 0, stream>>>(Q, P, qh, ql, ph, pl, invq, invp);
        mfma_gemm_kernel<<<2304, 512, 0, stream>>>(qh, ql, ph, pl, invq, invp,
                                                   out, row_best, col_best);
    } else {
        // workspace too small for split arrays: proven legacy path
        norms_kernel<<<N_PIX / 256, 256, 0, stream>>>(Q, P, invq, invp);
        dim3 grid(N_PIX / BN, N_PIX / BM);
        gemm_kernel<<<grid, 256, 0, stream>>>(Q, P, invq, invp, out, row_best, col_best);
    }

    epilogue_kernel<<<N_PIX / 256, 256, 0, stream>>>(row_best, col_best, out);
}

// Round 5
// 472.233 us; speedup vs baseline: 1.0287x; 1.0287x over previous
//
#include <hip/hip_runtime.h>
#include <hip/hip_fp16.h>

#define N_PIX 9216
#define CCH 256
#define W_ 96
#define H_ 96
#define BM 128
#define BN 128
#define BK 16
#define TM 8
#define TN 8

typedef _Float16 half8_t __attribute__((ext_vector_type(8)));
typedef float f32x4_t __attribute__((ext_vector_type(4)));

// Monotone encoding: unsigned compare order == float compare order.
__device__ __forceinline__ unsigned int mono_enc(float f) {
    unsigned int u = __float_as_uint(f);
    return (u & 0x80000000u) ? ~u : (u | 0x80000000u);
}
__device__ __forceinline__ float mono_dec(unsigned int e) {
    return __uint_as_float((e & 0x80000000u) ? (e ^ 0x80000000u) : ~e);
}

// async global->LDS, 16B per lane; LDS dest is wave-uniform base + lane*16.
__device__ __forceinline__ void gload_lds16(const uint4* g, uint4* lds) {
    __builtin_amdgcn_global_load_lds(
        (const __attribute__((address_space(1))) unsigned int*)g,
        (__attribute__((address_space(3))) unsigned int*)lds, 16, 0, 0);
}

// ======================= legacy (fallback) path =======================

__global__ __launch_bounds__(256) void norms_kernel(const float* __restrict__ Q,
                                                    const float* __restrict__ P,
                                                    float* __restrict__ invq,
                                                    float* __restrict__ invp) {
    int n = blockIdx.x * blockDim.x + threadIdx.x;
    if (n >= N_PIX) return;
    float sq = 0.f, sp = 0.f;
    for (int c = 0; c < CCH; ++c) {
        float a = Q[(size_t)c * N_PIX + n];
        float b = P[(size_t)c * N_PIX + n];
        sq = fmaf(a, a, sq);
        sp = fmaf(b, b, sp);
    }
    invq[n] = 1.0f / sqrtf(sq);
    invp[n] = 1.0f / sqrtf(sp);
}

__device__ __forceinline__ int local_row(int ty, int i) {
    return (i < 4) ? (ty * 4 + i) : (64 + ty * 4 + (i - 4));
}
__device__ __forceinline__ int local_col(int tx, int j) {
    return (j < 4) ? (tx * 4 + j) : (64 + tx * 4 + (j - 4));
}

__global__ __launch_bounds__(256) void gemm_kernel(const float* __restrict__ Q,
                                                   const float* __restrict__ P,
                                                   const float* __restrict__ invq,
                                                   const float* __restrict__ invp,
                                                   float* __restrict__ sim,
                                                   unsigned long long* __restrict__ row_best,
                                                   unsigned long long* __restrict__ col_best) {
    __shared__ union SH {
        struct { float A[BK][BM]; float B[BK][BN]; } t;
        unsigned long long red[16][128];
    } sh;

    const int tid = threadIdx.x;
    const int tx = tid & 15;
    const int ty = tid >> 4;
    const int n0 = blockIdx.y * BM;
    const int m0 = blockIdx.x * BN;

    float acc[TM][TN];
#pragma unroll
    for (int i = 0; i < TM; ++i)
#pragma unroll
        for (int j = 0; j < TN; ++j) acc[i][j] = 0.f;

    for (int kk = 0; kk < CCH; kk += BK) {
#pragma unroll
        for (int rep = 0; rep < 2; ++rep) {
            int idx = tid + rep * 256;
            int row = idx >> 5;
            int c4  = idx & 31;
            float4 av = *(const float4*)&Q[(size_t)(kk + row) * N_PIX + n0 + c4 * 4];
            float4 bv = *(const float4*)&P[(size_t)(kk + row) * N_PIX + m0 + c4 * 4];
            *(float4*)&sh.t.A[row][c4 * 4] = av;
            *(float4*)&sh.t.B[row][c4 * 4] = bv;
        }
        __syncthreads();
#pragma unroll
        for (int k = 0; k < BK; ++k) {
            float a[TM], b[TN];
            *(float4*)&a[0] = *(const float4*)&sh.t.A[k][ty * 4];
            *(float4*)&a[4] = *(const float4*)&sh.t.A[k][ty * 4 + 64];
            *(float4*)&b[0] = *(const float4*)&sh.t.B[k][tx * 4];
            *(float4*)&b[4] = *(const float4*)&sh.t.B[k][tx * 4 + 64];
#pragma unroll
            for (int i = 0; i < TM; ++i)
#pragma unroll
                for (int j = 0; j < TN; ++j)
                    acc[i][j] = fmaf(a[i], b[j], acc[i][j]);
        }
        __syncthreads();
    }

    float iq[TM], ip[TN];
#pragma unroll
    for (int i = 0; i < TM; ++i) iq[i] = invq[n0 + local_row(ty, i)];
#pragma unroll
    for (int j = 0; j < TN; ++j) ip[j] = invp[m0 + local_col(tx, j)];
#pragma unroll
    for (int i = 0; i < TM; ++i)
#pragma unroll
        for (int j = 0; j < TN; ++j) acc[i][j] *= iq[i] * ip[j];

#pragma unroll
    for (int i = 0; i < TM; ++i) {
        int n = n0 + local_row(ty, i);
        float4 v0 = make_float4(acc[i][0], acc[i][1], acc[i][2], acc[i][3]);
        float4 v1 = make_float4(acc[i][4], acc[i][5], acc[i][6], acc[i][7]);
        float* dst = &sim[(size_t)n * N_PIX + m0];
        *(float4*)(dst + tx * 4) = v0;
        *(float4*)(dst + 64 + tx * 4) = v1;
    }

#pragma unroll
    for (int i = 0; i < TM; ++i) {
        float best = acc[i][0]; int bj = 0;
#pragma unroll
        for (int j = 1; j < TN; ++j)
            if (acc[i][j] > best) { best = acc[i][j]; bj = j; }
        unsigned int gcol = (unsigned int)(m0 + local_col(tx, bj));
        sh.red[tx][local_row(ty, i)] =
            ((unsigned long long)mono_enc(best) << 32) | (unsigned long long)(0xFFFFFFFFu - gcol);
    }
    __syncthreads();
    if (tid < 128) {
        unsigned long long best = sh.red[0][tid];
#pragma unroll
        for (int x = 1; x < 16; ++x) {
            unsigned long long v = sh.red[x][tid];
            if (v > best) best = v;
        }
        atomicMax(&row_best[n0 + tid], best);
    }
    __syncthreads();

#pragma unroll
    for (int j = 0; j < TN; ++j) {
        float best = acc[0][j]; int bi = 0;
#pragma unroll
        for (int i = 1; i < TM; ++i)
            if (acc[i][j] > best) { best = acc[i][j]; bi = i; }
        unsigned int grow = (unsigned int)(n0 + local_row(ty, bi));
        sh.red[ty][local_col(tx, j)] =
            ((unsigned long long)mono_enc(best) << 32) | (unsigned long long)(0xFFFFFFFFu - grow);
    }
    __syncthreads();
    if (tid < 128) {
        unsigned long long best = sh.red[0][tid];
#pragma unroll
        for (int x = 1; x < 16; ++x) {
            unsigned long long v = sh.red[x][tid];
            if (v > best) best = v;
        }
        atomicMax(&col_best[m0 + tid], best);
    }
}

// ======================= fast (MFMA) path =======================

__device__ __forceinline__ unsigned int pack_pair(float x, float y, float& rx, float& ry) {
    __half hx = __float2half(x), hy = __float2half(y);
    rx = x - __half2float(hx);
    ry = y - __half2float(hy);
    return (unsigned int)__half_as_ushort(hx) | ((unsigned int)__half_as_ushort(hy) << 16);
}

// Fused norms + fp16-split + workspace-zero kernel, 576 blocks x 16 px.
// Output layout FRAGMENT-MAJOR (as before): array[kb*N_PIX + n] is a uint4 of
// 4 k-pair dwords (k = kb*8 .. kb*8+7) == one MFMA fragment register group.
__global__ __launch_bounds__(256) void prep_kernel(const float* __restrict__ Q,
                                                   const float* __restrict__ P,
                                                   uint4* __restrict__ qh,
                                                   uint4* __restrict__ ql,
                                                   uint4* __restrict__ ph,
                                                   uint4* __restrict__ pl,
                                                   float* __restrict__ invq,
                                                   float* __restrict__ invp,
                                                   unsigned long long* __restrict__ best01) {
    __shared__ float rq[16][17];
    __shared__ float rp[16][17];
    const int t = threadIdx.x;
    const int n16 = t & 15;
    const int ks = t >> 4;                 // 0..15 k-slab (2 kb rows each)
    const int n = blockIdx.x * 16 + n16;

    // zero argmax workspace: 576 blocks x 32 u64 == 2*N_PIX exactly
    if (t < 32) best01[blockIdx.x * 32 + t] = 0ULL;

    float sq = 0.f, sp = 0.f;
#pragma unroll
    for (int kk = 0; kk < 2; ++kk) {
        const int kb = ks * 2 + kk;
        float a[8], b[8];
#pragma unroll
        for (int u = 0; u < 8; ++u) {
            a[u] = Q[(size_t)(kb * 8 + u) * N_PIX + n];
            b[u] = P[(size_t)(kb * 8 + u) * N_PIX + n];
        }
#pragma unroll
        for (int u = 0; u < 8; ++u) {
            sq = fmaf(a[u], a[u], sq);
            sp = fmaf(b[u], b[u], sp);
        }
        uint4 vqh, vql, vph, vpl;
        unsigned int* uqh = (unsigned int*)&vqh;
        unsigned int* uql = (unsigned int*)&vql;
        unsigned int* uph = (unsigned int*)&vph;
        unsigned int* upl = (unsigned int*)&vpl;
#pragma unroll
        for (int j = 0; j < 4; ++j) {
            float r0, r1;
            uqh[j] = pack_pair(a[2 * j], a[2 * j + 1], r0, r1);
            uql[j] = (unsigned int)__half_as_ushort(__float2half(r0))
                   | ((unsigned int)__half_as_ushort(__float2half(r1)) << 16);
            uph[j] = pack_pair(b[2 * j], b[2 * j + 1], r0, r1);
            upl[j] = (unsigned int)__half_as_ushort(__float2half(r0))
                   | ((unsigned int)__half_as_ushort(__float2half(r1)) << 16);
        }
        size_t o = (size_t)kb * N_PIX + n;
        qh[o] = vqh; ql[o] = vql; ph[o] = vph; pl[o] = vpl;
    }
    rq[ks][n16] = sq;
    rp[ks][n16] = sp;
    __syncthreads();
    if (t < 16) {
        float s = 0.f;
#pragma unroll
        for (int x = 0; x < 16; ++x) s += rq[x][t];
        invq[blockIdx.x * 16 + t] = 1.0f / sqrtf(s);
    } else if (t < 32) {
        const int tt = t - 16;
        float s = 0.f;
#pragma unroll
        for (int x = 0; x < 16; ++x) s += rp[x][tt];
        invp[blockIdx.x * 16 + tt] = 1.0f / sqrtf(s);
    }
}

// 128x128 tile, 4 waves, wave = 64x64 = 4x4 fragments of 16x16x32 f16 MFMA.
// 3-term fp16 split (hi*hi + hi*lo + lo*hi).
// Schedule: A operands load DIRECT global->registers (L1/L2-hot across bx
// neighbors), B operands stage through 3x16KB LDS buffers with depth-2
// prefetch via global_load_lds. One RAW s_barrier per K-step (no compiler
// vmcnt/lgkm drain); correctness of the staging handoff follows from
// in-order VMEM retirement: each step's MFMA waits on A-regs that were
// issued AFTER the previous step's B-stage loads, so by barrier time the
// next buffer is resident in every wave.
__global__ __launch_bounds__(256, 2) void mfma_gemm_kernel(
        const uint4* __restrict__ QH, const uint4* __restrict__ QL,
        const uint4* __restrict__ PH, const uint4* __restrict__ PL,
        const float* __restrict__ invq, const float* __restrict__ invp,
        float* __restrict__ sim,
        unsigned long long* __restrict__ row_best,
        unsigned long long* __restrict__ col_best) {
    // Serpentine XCD swizzle (as r3): 5184 blocks = 8 XCDs x 648.
    const unsigned int bid = blockIdx.x;
    const unsigned int xcd = bid & 7u;
    const unsigned int nbl = bid >> 3;           // 0..647
    const unsigned int gg  = nbl / 72u;          // 0..8  bx-group
    const unsigned int rr  = nbl % 72u;
    const unsigned int by  = xcd * 9u + (rr >> 3);   // 0..71
    const unsigned int bx  = gg * 8u + (rr & 7u);    // 0..71

    const int tid = threadIdx.x;
    const int l  = tid & 63;
    const int w  = tid >> 6;   // 0..3
    const int rl = l & 15;     // fragment row (A) / col (B,D)
    const int kg = l >> 4;     // k-group; also D-row group
    const int n0 = (int)by * 128;
    const int m0 = (int)bx * 128;
    const int r0 = n0 + (w >> 1) * 64;   // wave row base
    const int c0 = m0 + (w & 1) * 64;    // wave col base

    // B stage: [3 bufs][arr Ph,Pl][kb 0..3][pixel 0..127] = 48 KB,
    // union'd with per-wave store-transpose buffer (used after the loop).
    __shared__ union SH2 {
        uint4 bstage[3][2][4][128];
        float st[4][16][68];
    } sh;

    f32x4_t acc[4][4];
#pragma unroll
    for (int i = 0; i < 4; ++i)
#pragma unroll
        for (int j = 0; j < 4; ++j) acc[i][j] = {0.f, 0.f, 0.f, 0.f};

    // --- B staging assignment: wave w -> arr = w&1 (PH/PL), px-half = w>>1
    const int sarr  = w & 1;
    const int shalf = w >> 1;
    const uint4* bptr = ((sarr == 0) ? PH : PL) + m0 + shalf * 64;

#define BSTAGE(t_, b_)                                                          \
    {                                                                           \
        _Pragma("unroll")                                                       \
        for (int kb = 0; kb < 4; ++kb)                                          \
            gload_lds16(bptr + (size_t)((t_) * 4 + kb) * N_PIX + l,             \
                        &sh.bstage[b_][sarr][kb][shalf * 64]);                  \
    }

    // --- A direct loads (global -> regs), double-buffered by K-step parity
    union Frag { uint4 u; half8_t h; };
    Frag ahA[4], alA[4], ahB[4], alB[4];
    const uint4* qhp = QH + r0 + rl;
    const uint4* qlp = QL + r0 + rl;

#define ALOAD(t_, dh_, dl_)                                                     \
    {                                                                           \
        _Pragma("unroll")                                                       \
        for (int f = 0; f < 4; ++f) {                                           \
            dh_[f].u = qhp[(size_t)((t_) * 4 + kg) * N_PIX + f * 16];           \
            dl_[f].u = qlp[(size_t)((t_) * 4 + kg) * N_PIX + f * 16];           \
        }                                                                       \
    }

    // prologue: B(0)->buf0, B(1)->buf1, A(0)->set A; wait B(0), barrier
    BSTAGE(0, 0)
    BSTAGE(1, 1)
    ALOAD(0, ahA, alA)
    asm volatile("s_waitcnt vmcnt(12)" ::: "memory");  // retire B(0) (oldest 4)
    __builtin_amdgcn_s_barrier();
    __builtin_amdgcn_sched_barrier(0);

#pragma unroll
    for (int s = 0; s < 8; ++s) {
        if (s < 6) BSTAGE(s + 2, (s + 2) % 3)          // depth-2 B prefetch
        if (s < 7) {                                   // next A into other set
            if (s & 1) { ALOAD(s + 1, ahA, alA) }
            else       { ALOAD(s + 1, ahB, alB) }
        }
        Frag (&ah)[4] = (s & 1) ? ahB : ahA;
        Frag (&al)[4] = (s & 1) ? alB : alA;

        half8_t bh_[4], bl_[4];
#pragma unroll
        for (int f = 0; f < 4; ++f) {
            bh_[f] = *(const half8_t*)&sh.bstage[s % 3][0][kg][(w & 1) * 64 + f * 16 + rl];
            bl_[f] = *(const half8_t*)&sh.bstage[s % 3][1][kg][(w & 1) * 64 + f * 16 + rl];
        }

        __builtin_amdgcn_s_setprio(1);
#pragma unroll
        for (int fr = 0; fr < 4; ++fr)
#pragma unroll
            for (int fc = 0; fc < 4; ++fc) {
                acc[fr][fc] = __builtin_amdgcn_mfma_f32_16x16x32_f16(ah[fr].h, bh_[fc], acc[fr][fc], 0, 0, 0);
                acc[fr][fc] = __builtin_amdgcn_mfma_f32_16x16x32_f16(ah[fr].h, bl_[fc], acc[fr][fc], 0, 0, 0);
                acc[fr][fc] = __builtin_amdgcn_mfma_f32_16x16x32_f16(al[fr].h, bh_[fc], acc[fr][fc], 0, 0, 0);
            }
        __builtin_amdgcn_s_setprio(0);

        // raw barrier: MFMA's A-reg waits already retired B(s+1) (issued
        // earlier in program order; VMEM retires in order) -> no drain needed.
        __builtin_amdgcn_s_barrier();
        __builtin_amdgcn_sched_barrier(0);
    }
#undef BSTAGE
#undef ALOAD

    // ---- scale by inverse norms (in-register) ----
    float iq[4][4];
#pragma unroll
    for (int fr = 0; fr < 4; ++fr) {
        const float4 v = *(const float4*)&invq[r0 + fr * 16 + kg * 4];
        iq[fr][0] = v.x; iq[fr][1] = v.y; iq[fr][2] = v.z; iq[fr][3] = v.w;
    }
    float ip[4];
#pragma unroll
    for (int fc = 0; fc < 4; ++fc) ip[fc] = invp[c0 + fc * 16 + rl];

#pragma unroll
    for (int fr = 0; fr < 4; ++fr)
#pragma unroll
        for (int fc = 0; fc < 4; ++fc)
#pragma unroll
            for (int j = 0; j < 4; ++j)
                acc[fr][fc][j] *= iq[fr][j] * ip[fc];

    // ---- row bests: reduce over this wave's 64 cols (fc in-lane, rl x-lane) ----
#pragma unroll
    for (int fr = 0; fr < 4; ++fr)
#pragma unroll
        for (int j = 0; j < 4; ++j) {
            float best = acc[fr][0][j];
            int bf = 0;
#pragma unroll
            for (int fc = 1; fc < 4; ++fc)
                if (acc[fr][fc][j] > best) { best = acc[fr][fc][j]; bf = fc; }
            const unsigned int gcol = (unsigned int)(c0 + bf * 16 + rl);
            unsigned long long key = ((unsigned long long)mono_enc(best) << 32)
                                   | (unsigned long long)(0xFFFFFFFFu - gcol);
#pragma unroll
            for (int m = 1; m < 16; m <<= 1) {
                unsigned long long o = __shfl_xor(key, m, 64);
                if (o > key) key = o;
            }
            if (rl == 0)
                atomicMax(&row_best[r0 + fr * 16 + kg * 4 + j], key);
        }

    // ---- col bests: reduce over this wave's 64 rows (fr,j in-lane, kg x-lane) ----
#pragma unroll
    for (int fc = 0; fc < 4; ++fc) {
        float best = acc[0][fc][0];
        unsigned int brow = (unsigned int)(r0 + kg * 4);
#pragma unroll
        for (int fr = 0; fr < 4; ++fr)
#pragma unroll
            for (int j = 0; j < 4; ++j) {
                float v = acc[fr][fc][j];  // rows scanned in increasing order
                unsigned int rr2 = (unsigned int)(r0 + fr * 16 + kg * 4 + j);
                if (v > best) { best = v; brow = rr2; }
            }
        unsigned long long key = ((unsigned long long)mono_enc(best) << 32)
                               | (unsigned long long)(0xFFFFFFFFu - brow);
#pragma unroll
        for (int m = 16; m < 64; m <<= 1) {
            unsigned long long o = __shfl_xor(key, m, 64);
            if (o > key) key = o;
        }
        if (kg == 0)
            atomicMax(&col_best[c0 + fc * 16 + rl], key);
    }

    // ---- sim stores via per-wave LDS transpose: full-line writes ----
    // (stage buffers dead: loop's final barrier passed; all stage loads retired)
#pragma unroll
    for (int fr = 0; fr < 4; ++fr) {
        asm volatile("s_waitcnt lgkmcnt(0)" ::: "memory");  // prior fr's reads done
#pragma unroll
        for (int fc = 0; fc < 4; ++fc)
#pragma unroll
            for (int j = 0; j < 4; ++j)
                sh.st[w][kg * 4 + j][fc * 16 + rl] = acc[fr][fc][j];
        asm volatile("s_waitcnt lgkmcnt(0)" ::: "memory");  // writes visible to wave
#pragma unroll
        for (int pass = 0; pass < 4; ++pass) {
            const int rowL = pass * 4 + kg;
            const f32x4_t v = *(const f32x4_t*)&sh.st[w][rowL][rl * 4];
            const int gr = r0 + fr * 16 + rowL;
            // 16 lanes (rl) x 16 B contiguous per row = 256 B runs, 4 rows/inst
            __builtin_nontemporal_store(v, (f32x4_t*)(sim + (size_t)gr * N_PIX + c0 + rl * 4));
        }
    }
}

// ======================= shared epilogue =======================

__global__ __launch_bounds__(256) void epilogue_kernel(const unsigned long long* __restrict__ row_best,
                                                       const unsigned long long* __restrict__ col_best,
                                                       float* __restrict__ out) {
    int j = blockIdx.x * blockDim.x + threadIdx.x;
    if (j >= N_PIX) return;
    unsigned long long cb = col_best[j];
    unsigned int q_idx = 0xFFFFFFFFu - (unsigned int)(cb & 0xFFFFFFFFull);
    float simval = mono_dec((unsigned int)(cb >> 32));
    unsigned long long rb = row_best[q_idx];
    unsigned int rm = 0xFFFFFFFFu - (unsigned int)(rb & 0xFFFFFFFFull);
    bool mutual = (rm == (unsigned int)j) && (simval > 0.9f);
    int qd = (int)(q_idx / W_), qm = (int)(q_idx % W_);
    int pd = j / W_, pm = j % W_;
    bool valid = mutual && (qd + 1 < H_) && (pd + 1 < H_);
    size_t base = (size_t)N_PIX * N_PIX;
    out[base + 0 * (size_t)N_PIX + j] = valid ? 1.0f : 0.0f;
    out[base + 1 * (size_t)N_PIX + j] = (float)q_idx;
    out[base + 2 * (size_t)N_PIX + j] = (float)qd;
    out[base + 3 * (size_t)N_PIX + j] = (float)qm;
    out[base + 4 * (size_t)N_PIX + j] = (float)pd;
    out[base + 5 * (size_t)N_PIX + j] = (float)pm;
}

extern "C" void kernel_launch(void* const* d_in, const int* in_sizes, int n_in,
                              void* d_out, int out_size, void* d_ws, size_t ws_size,
                              hipStream_t stream) {
    const float* Q = (const float*)d_in[0];
    const float* P = (const float*)d_in[1];
    float* out = (float*)d_out;

    unsigned long long* row_best = (unsigned long long*)d_ws;
    unsigned long long* col_best = row_best + N_PIX;
    float* invq = (float*)(col_best + N_PIX);
    float* invp = invq + N_PIX;

    const size_t base_bytes = 2 * N_PIX * sizeof(unsigned long long) + 2 * N_PIX * sizeof(float);
    const size_t arr_u4 = (size_t)(CCH / 8) * N_PIX;  // 32 kb-rows x N uint4
    const size_t need = base_bytes + 4 * arr_u4 * sizeof(uint4);

    if (ws_size >= need) {
        uint4* qh = (uint4*)((char*)d_ws + base_bytes);
        uint4* ql = qh + arr_u4;
        uint4* ph = ql + arr_u4;
        uint4* pl = ph + arr_u4;

        // prep zeroes row/col_best itself (576 blocks x 32 u64 == 2*N_PIX)
        prep_kernel<<<N_PIX / 16, 256, 0, stream>>>(Q, P, qh, ql, ph, pl, invq, invp,
                                                    (unsigned long long*)d_ws);
        mfma_gemm_kernel<<<5184, 256, 0, stream>>>(qh, ql, ph, pl, invq, invp,
                                                   out, row_best, col_best);
    } else {
        // workspace too small for split arrays: proven legacy path
        hipMemsetAsync(d_ws, 0, 2 * N_PIX * sizeof(unsigned long long), stream);
        norms_kernel<<<N_PIX / 256, 256, 0, stream>>>(Q, P, invq, invp);
        dim3 grid(N_PIX / BN, N_PIX / BM);
        gemm_kernel<<<grid, 256, 0, stream>>>(Q, P, invq, invp, out, row_best, col_best);
    }

    epilogue_kernel<<<N_PIX / 256, 256, 0, stream>>>(row_best, col_best, out);
}

// Round 6
// 465.750 us; speedup vs baseline: 1.0430x; 1.0139x over previous
//
#include <hip/hip_runtime.h>
#include <hip/hip_fp16.h>

#define N_PIX 9216
#define CCH 256
#define W_ 96
#define H_ 96
#define BM 128
#define BN 128
#define BK 16
#define TM 8
#define TN 8

typedef _Float16 half8_t __attribute__((ext_vector_type(8)));
typedef float f32x4_t __attribute__((ext_vector_type(4)));

// Monotone encoding: unsigned compare order == float compare order.
__device__ __forceinline__ unsigned int mono_enc(float f) {
    unsigned int u = __float_as_uint(f);
    return (u & 0x80000000u) ? ~u : (u | 0x80000000u);
}
__device__ __forceinline__ float mono_dec(unsigned int e) {
    return __uint_as_float((e & 0x80000000u) ? (e ^ 0x80000000u) : ~e);
}

// async global->LDS, 16B per lane; LDS dest is wave-uniform base + lane*16.
__device__ __forceinline__ void gload_lds16(const uint4* g, uint4* lds) {
    __builtin_amdgcn_global_load_lds(
        (const __attribute__((address_space(1))) unsigned int*)g,
        (__attribute__((address_space(3))) unsigned int*)lds, 16, 0, 0);
}

// ======================= legacy (fallback) path =======================

__global__ __launch_bounds__(256) void norms_kernel(const float* __restrict__ Q,
                                                    const float* __restrict__ P,
                                                    float* __restrict__ invq,
                                                    float* __restrict__ invp) {
    int n = blockIdx.x * blockDim.x + threadIdx.x;
    if (n >= N_PIX) return;
    float sq = 0.f, sp = 0.f;
    for (int c = 0; c < CCH; ++c) {
        float a = Q[(size_t)c * N_PIX + n];
        float b = P[(size_t)c * N_PIX + n];
        sq = fmaf(a, a, sq);
        sp = fmaf(b, b, sp);
    }
    invq[n] = 1.0f / sqrtf(sq);
    invp[n] = 1.0f / sqrtf(sp);
}

__device__ __forceinline__ int local_row(int ty, int i) {
    return (i < 4) ? (ty * 4 + i) : (64 + ty * 4 + (i - 4));
}
__device__ __forceinline__ int local_col(int tx, int j) {
    return (j < 4) ? (tx * 4 + j) : (64 + tx * 4 + (j - 4));
}

__global__ __launch_bounds__(256) void gemm_kernel(const float* __restrict__ Q,
                                                   const float* __restrict__ P,
                                                   const float* __restrict__ invq,
                                                   const float* __restrict__ invp,
                                                   float* __restrict__ sim,
                                                   unsigned long long* __restrict__ row_best,
                                                   unsigned long long* __restrict__ col_best) {
    __shared__ union SH {
        struct { float A[BK][BM]; float B[BK][BN]; } t;
        unsigned long long red[16][128];
    } sh;

    const int tid = threadIdx.x;
    const int tx = tid & 15;
    const int ty = tid >> 4;
    const int n0 = blockIdx.y * BM;
    const int m0 = blockIdx.x * BN;

    float acc[TM][TN];
#pragma unroll
    for (int i = 0; i < TM; ++i)
#pragma unroll
        for (int j = 0; j < TN; ++j) acc[i][j] = 0.f;

    for (int kk = 0; kk < CCH; kk += BK) {
#pragma unroll
        for (int rep = 0; rep < 2; ++rep) {
            int idx = tid + rep * 256;
            int row = idx >> 5;
            int c4  = idx & 31;
            float4 av = *(const float4*)&Q[(size_t)(kk + row) * N_PIX + n0 + c4 * 4];
            float4 bv = *(const float4*)&P[(size_t)(kk + row) * N_PIX + m0 + c4 * 4];
            *(float4*)&sh.t.A[row][c4 * 4] = av;
            *(float4*)&sh.t.B[row][c4 * 4] = bv;
        }
        __syncthreads();
#pragma unroll
        for (int k = 0; k < BK; ++k) {
            float a[TM], b[TN];
            *(float4*)&a[0] = *(const float4*)&sh.t.A[k][ty * 4];
            *(float4*)&a[4] = *(const float4*)&sh.t.A[k][ty * 4 + 64];
            *(float4*)&b[0] = *(const float4*)&sh.t.B[k][tx * 4];
            *(float4*)&b[4] = *(const float4*)&sh.t.B[k][tx * 4 + 64];
#pragma unroll
            for (int i = 0; i < TM; ++i)
#pragma unroll
                for (int j = 0; j < TN; ++j)
                    acc[i][j] = fmaf(a[i], b[j], acc[i][j]);
        }
        __syncthreads();
    }

    float iq[TM], ip[TN];
#pragma unroll
    for (int i = 0; i < TM; ++i) iq[i] = invq[n0 + local_row(ty, i)];
#pragma unroll
    for (int j = 0; j < TN; ++j) ip[j] = invp[m0 + local_col(tx, j)];
#pragma unroll
    for (int i = 0; i < TM; ++i)
#pragma unroll
        for (int j = 0; j < TN; ++j) acc[i][j] *= iq[i] * ip[j];

#pragma unroll
    for (int i = 0; i < TM; ++i) {
        int n = n0 + local_row(ty, i);
        float4 v0 = make_float4(acc[i][0], acc[i][1], acc[i][2], acc[i][3]);
        float4 v1 = make_float4(acc[i][4], acc[i][5], acc[i][6], acc[i][7]);
        float* dst = &sim[(size_t)n * N_PIX + m0];
        *(float4*)(dst + tx * 4) = v0;
        *(float4*)(dst + 64 + tx * 4) = v1;
    }

#pragma unroll
    for (int i = 0; i < TM; ++i) {
        float best = acc[i][0]; int bj = 0;
#pragma unroll
        for (int j = 1; j < TN; ++j)
            if (acc[i][j] > best) { best = acc[i][j]; bj = j; }
        unsigned int gcol = (unsigned int)(m0 + local_col(tx, bj));
        sh.red[tx][local_row(ty, i)] =
            ((unsigned long long)mono_enc(best) << 32) | (unsigned long long)(0xFFFFFFFFu - gcol);
    }
    __syncthreads();
    if (tid < 128) {
        unsigned long long best = sh.red[0][tid];
#pragma unroll
        for (int x = 1; x < 16; ++x) {
            unsigned long long v = sh.red[x][tid];
            if (v > best) best = v;
        }
        atomicMax(&row_best[n0 + tid], best);
    }
    __syncthreads();

#pragma unroll
    for (int j = 0; j < TN; ++j) {
        float best = acc[0][j]; int bi = 0;
#pragma unroll
        for (int i = 1; i < TM; ++i)
            if (acc[i][j] > best) { best = acc[i][j]; bi = i; }
        unsigned int grow = (unsigned int)(n0 + local_row(ty, bi));
        sh.red[ty][local_col(tx, j)] =
            ((unsigned long long)mono_enc(best) << 32) | (unsigned long long)(0xFFFFFFFFu - grow);
    }
    __syncthreads();
    if (tid < 128) {
        unsigned long long best = sh.red[0][tid];
#pragma unroll
        for (int x = 1; x < 16; ++x) {
            unsigned long long v = sh.red[x][tid];
            if (v > best) best = v;
        }
        atomicMax(&col_best[m0 + tid], best);
    }
}

// ======================= fast (MFMA) path =======================

__device__ __forceinline__ unsigned int pack_pair(float x, float y, float& rx, float& ry) {
    __half hx = __float2half(x), hy = __float2half(y);
    rx = x - __half2float(hx);
    ry = y - __half2float(hy);
    return (unsigned int)__half_as_ushort(hx) | ((unsigned int)__half_as_ushort(hy) << 16);
}

// Fused norms + fp16-split + workspace-zero kernel, 576 blocks x 16 px.
// Output layout FRAGMENT-MAJOR: array[kb*N_PIX + n] is a uint4 of 4 k-pair
// dwords (k = kb*8 .. kb*8+7) == one MFMA fragment register group.
__global__ __launch_bounds__(256) void prep_kernel(const float* __restrict__ Q,
                                                   const float* __restrict__ P,
                                                   uint4* __restrict__ qh,
                                                   uint4* __restrict__ ql,
                                                   uint4* __restrict__ ph,
                                                   uint4* __restrict__ pl,
                                                   float* __restrict__ invq,
                                                   float* __restrict__ invp,
                                                   unsigned long long* __restrict__ best01) {
    __shared__ float rq[16][17];
    __shared__ float rp[16][17];
    const int t = threadIdx.x;
    const int n16 = t & 15;
    const int ks = t >> 4;                 // 0..15 k-slab (2 kb rows each)
    const int n = blockIdx.x * 16 + n16;

    // zero argmax workspace: 576 blocks x 32 u64 == 2*N_PIX exactly
    if (t < 32) best01[blockIdx.x * 32 + t] = 0ULL;

    float sq = 0.f, sp = 0.f;
#pragma unroll
    for (int kk = 0; kk < 2; ++kk) {
        const int kb = ks * 2 + kk;
        float a[8], b[8];
#pragma unroll
        for (int u = 0; u < 8; ++u) {
            a[u] = Q[(size_t)(kb * 8 + u) * N_PIX + n];
            b[u] = P[(size_t)(kb * 8 + u) * N_PIX + n];
        }
#pragma unroll
        for (int u = 0; u < 8; ++u) {
            sq = fmaf(a[u], a[u], sq);
            sp = fmaf(b[u], b[u], sp);
        }
        uint4 vqh, vql, vph, vpl;
        unsigned int* uqh = (unsigned int*)&vqh;
        unsigned int* uql = (unsigned int*)&vql;
        unsigned int* uph = (unsigned int*)&vph;
        unsigned int* upl = (unsigned int*)&vpl;
#pragma unroll
        for (int j = 0; j < 4; ++j) {
            float r0, r1;
            uqh[j] = pack_pair(a[2 * j], a[2 * j + 1], r0, r1);
            uql[j] = (unsigned int)__half_as_ushort(__float2half(r0))
                   | ((unsigned int)__half_as_ushort(__float2half(r1)) << 16);
            uph[j] = pack_pair(b[2 * j], b[2 * j + 1], r0, r1);
            upl[j] = (unsigned int)__half_as_ushort(__float2half(r0))
                   | ((unsigned int)__half_as_ushort(__float2half(r1)) << 16);
        }
        size_t o = (size_t)kb * N_PIX + n;
        qh[o] = vqh; ql[o] = vql; ph[o] = vph; pl[o] = vpl;
    }
    rq[ks][n16] = sq;
    rp[ks][n16] = sp;
    __syncthreads();
    if (t < 16) {
        float s = 0.f;
#pragma unroll
        for (int x = 0; x < 16; ++x) s += rq[x][t];
        invq[blockIdx.x * 16 + t] = 1.0f / sqrtf(s);
    } else if (t < 32) {
        const int tt = t - 16;
        float s = 0.f;
#pragma unroll
        for (int x = 0; x < 16; ++x) s += rp[x][tt];
        invp[blockIdx.x * 16 + tt] = 1.0f / sqrtf(s);
    }
}

// 192x192 tile, 8 waves (512 thr), wave = 48 rows x 96 cols = 3x6 frags of
// 16x16x32 f16 MFMA. Grid 48x48 = 2304 = EXACTLY 9 rounds of 256 CUs.
//
// Fine-grained counted-vmcnt schedule (T3+T4): 3 phases per K-tile (K=32),
// partitioned by split TERM so each phase's LDS reads are gated by stage
// chunks issued >=1 tile earlier:
//   P0: A_hi x B_hi   (reads A_hi + B_hi;  needs chunks 0-2)
//   P1: A_hi x B_lo   (reads B_lo only;    needs chunks 3-4; A_hi in regs)
//   P2: A_lo x B_hi   (reads A_lo only;    needs chunk  5;  B_hi in regs)
// Stage buffer/tile = 48 KB = 6 chunks of 8 KB, memory order
// [A_hi 12K | B_hi 12K | B_lo 12K | A_lo 12K], double-buffered (96 KB).
// Per phase: {asm vmcnt(N) + raw s_barrier + sched_barrier} -> issue 2
// next-tile chunks -> ds_read frags -> setprio(1) 18 MFMA setprio(0).
// Per-wave vmcnt ledger (every thread stages 16 B of every chunk):
//   steady state entries: P0 vmcnt(3), P1 vmcnt(3), P2 vmcnt(4)  (never 0)
//   last tile (no issues): 3 / 1 / 0.
__global__ __launch_bounds__(512, 2) void mfma_gemm_kernel(
        const uint4* __restrict__ QH, const uint4* __restrict__ QL,
        const uint4* __restrict__ PH, const uint4* __restrict__ PL,
        const float* __restrict__ invq, const float* __restrict__ invp,
        float* __restrict__ sim,
        unsigned long long* __restrict__ row_best,
        unsigned long long* __restrict__ col_best) {
    // XCD swizzle (2304 % 8 == 0): each XCD owns 6 by-rows x 48 bx, walked in
    // 8-wide bx groups -> resident set ~2 MB per XCD L2.
    const unsigned int bid = blockIdx.x;
    const unsigned int xcd = bid & 7u;
    const unsigned int nbl = bid >> 3;          // 0..287
    const unsigned int g   = nbl >> 3;          // 0..35
    const unsigned int ii  = nbl & 7u;          // 0..7
    const unsigned int by  = xcd * 6u + g % 6u;     // 0..47
    const unsigned int bx  = (g / 6u) * 8u + ii;    // 0..47

    const int tid = threadIdx.x;
    const int l  = tid & 63;
    const int w  = tid >> 6;   // 0..7
    const int rl = l & 15;     // fragment row (A) / col (B,D)
    const int kg = l >> 4;     // k-group; also D-row group
    const int wr = w >> 1;     // 0..3 wave-row
    const int wc = w & 1;      // 0..1 wave-col
    const int n0 = (int)by * 192;
    const int m0 = (int)bx * 192;
    const int r0 = n0 + wr * 48;   // wave row base
    const int c0 = m0 + wc * 96;   // wave col base

    // 2 x 3072 uint4 = 96 KB stage; st (51.2 KB) reused after the loop.
    __shared__ union SH2 {
        uint4 stage[2][3072];
        float st[8][16][100];
    } sh;

    f32x4_t acc[3][6];
#pragma unroll
    for (int i = 0; i < 3; ++i)
#pragma unroll
        for (int j = 0; j < 6; ++j) acc[i][j] = {0.f, 0.f, 0.f, 0.f};

    // per-thread global sources for the 6 chunks (flat slot f = c*512 + tid)
    // regions (uint4 units): A_hi [0,768) B_hi [768,1536) B_lo [1536,2304) A_lo [2304,3072)
    const uint4* srcc[6];
#pragma unroll
    for (int c = 0; c < 6; ++c) {
        const int f = c * 512 + tid;
        const int r = f / 768;
        const int gg2 = f - r * 768;
        const int kb = gg2 / 192;
        const int px = gg2 - kb * 192;
        const uint4* base = (r == 0) ? (QH + n0) : (r == 1) ? (PH + m0)
                          : (r == 2) ? (PL + m0) : (QL + n0);
        srcc[c] = base + (size_t)kb * N_PIX + px;
    }

#define ISSUE2(cA, cB, wb)                                                     \
    gload_lds16(srcc[cA], &sh.stage[wb][(cA) * 512 + w * 64]);                 \
    gload_lds16(srcc[cB], &sh.stage[wb][(cB) * 512 + w * 64]);

#define ENTRY(N)                                                               \
    asm volatile("s_waitcnt vmcnt(" #N ")" ::: "memory");                      \
    __builtin_amdgcn_s_barrier();                                              \
    __builtin_amdgcn_sched_barrier(0);

    // prologue: stage tile 0 (6 chunks) into buf 0
#pragma unroll
    for (int c = 0; c < 6; ++c)
        gload_lds16(srcc[c], &sh.stage[0][c * 512 + w * 64]);
#pragma unroll
    for (int c = 0; c < 6; ++c) srcc[c] += (size_t)4 * N_PIX;

    const int aoff = kg * 192 + wr * 48 + rl;   // A frag base (uint4 idx)
    const int boff = kg * 192 + wc * 96 + rl;   // B frag base

#pragma unroll
    for (int t = 0; t < 8; ++t) {
        const int rb = t & 1, wb = (t + 1) & 1;
        const uint4* Bb = &sh.stage[rb][0];
        half8_t ahi[3], bhi[6];

        // ---- P0: A_hi x B_hi ----
        ENTRY(3)
        if (t < 7) { ISSUE2(0, 1, wb) }
#pragma unroll
        for (int fr = 0; fr < 3; ++fr) ahi[fr] = *(const half8_t*)&Bb[aoff + fr * 16];
#pragma unroll
        for (int fc = 0; fc < 6; ++fc) bhi[fc] = *(const half8_t*)&Bb[768 + boff + fc * 16];
        __builtin_amdgcn_s_setprio(1);
#pragma unroll
        for (int fr = 0; fr < 3; ++fr)
#pragma unroll
            for (int fc = 0; fc < 6; ++fc)
                acc[fr][fc] = __builtin_amdgcn_mfma_f32_16x16x32_f16(ahi[fr], bhi[fc], acc[fr][fc], 0, 0, 0);
        __builtin_amdgcn_s_setprio(0);

        // ---- P1: A_hi x B_lo ----
        if (t < 7) { ENTRY(3) } else { ENTRY(1) }
        if (t < 7) { ISSUE2(2, 3, wb) }
        {
            half8_t blo[6];
#pragma unroll
            for (int fc = 0; fc < 6; ++fc) blo[fc] = *(const half8_t*)&Bb[1536 + boff + fc * 16];
            __builtin_amdgcn_s_setprio(1);
#pragma unroll
            for (int fr = 0; fr < 3; ++fr)
#pragma unroll
                for (int fc = 0; fc < 6; ++fc)
                    acc[fr][fc] = __builtin_amdgcn_mfma_f32_16x16x32_f16(ahi[fr], blo[fc], acc[fr][fc], 0, 0, 0);
            __builtin_amdgcn_s_setprio(0);
        }

        // ---- P2: A_lo x B_hi ----
        if (t < 7) { ENTRY(4) } else { ENTRY(0) }
        if (t < 7) { ISSUE2(4, 5, wb) }
        {
            half8_t alo[3];
#pragma unroll
            for (int fr = 0; fr < 3; ++fr) alo[fr] = *(const half8_t*)&Bb[2304 + aoff + fr * 16];
            __builtin_amdgcn_s_setprio(1);
#pragma unroll
            for (int fr = 0; fr < 3; ++fr)
#pragma unroll
                for (int fc = 0; fc < 6; ++fc)
                    acc[fr][fc] = __builtin_amdgcn_mfma_f32_16x16x32_f16(alo[fr], bhi[fc], acc[fr][fc], 0, 0, 0);
            __builtin_amdgcn_s_setprio(0);
        }

        if (t < 7) {
#pragma unroll
            for (int c = 0; c < 6; ++c) srcc[c] += (size_t)4 * N_PIX;
        }
    }
#undef ISSUE2
#undef ENTRY

    // ---- scale by inverse norms (in-register) ----
    float iq[3][4];
#pragma unroll
    for (int fr = 0; fr < 3; ++fr) {
        const float4 v = *(const float4*)&invq[r0 + fr * 16 + kg * 4];
        iq[fr][0] = v.x; iq[fr][1] = v.y; iq[fr][2] = v.z; iq[fr][3] = v.w;
    }
    float ip[6];
#pragma unroll
    for (int fc = 0; fc < 6; ++fc) ip[fc] = invp[c0 + fc * 16 + rl];

#pragma unroll
    for (int fr = 0; fr < 3; ++fr)
#pragma unroll
        for (int fc = 0; fc < 6; ++fc)
#pragma unroll
            for (int j = 0; j < 4; ++j)
                acc[fr][fc][j] *= iq[fr][j] * ip[fc];

    // ---- row bests: reduce over this wave's 96 cols (fc in-lane, rl x-lane) ----
#pragma unroll
    for (int fr = 0; fr < 3; ++fr)
#pragma unroll
        for (int j = 0; j < 4; ++j) {
            float best = acc[fr][0][j];
            int bf = 0;
#pragma unroll
            for (int fc = 1; fc < 6; ++fc)
                if (acc[fr][fc][j] > best) { best = acc[fr][fc][j]; bf = fc; }
            const unsigned int gcol = (unsigned int)(c0 + bf * 16 + rl);
            unsigned long long key = ((unsigned long long)mono_enc(best) << 32)
                                   | (unsigned long long)(0xFFFFFFFFu - gcol);
#pragma unroll
            for (int m = 1; m < 16; m <<= 1) {
                unsigned long long o = __shfl_xor(key, m, 64);
                if (o > key) key = o;
            }
            if (rl == 0)
                atomicMax(&row_best[r0 + fr * 16 + kg * 4 + j], key);
        }

    // ---- col bests: reduce over this wave's 48 rows (fr,j in-lane, kg x-lane) ----
#pragma unroll
    for (int fc = 0; fc < 6; ++fc) {
        float best = acc[0][fc][0];
        unsigned int brow = (unsigned int)(r0 + kg * 4);
#pragma unroll
        for (int fr = 0; fr < 3; ++fr)
#pragma unroll
            for (int j = 0; j < 4; ++j) {
                float v = acc[fr][fc][j];  // rows scanned in increasing order
                unsigned int rr2 = (unsigned int)(r0 + fr * 16 + kg * 4 + j);
                if (v > best) { best = v; brow = rr2; }
            }
        unsigned long long key = ((unsigned long long)mono_enc(best) << 32)
                               | (unsigned long long)(0xFFFFFFFFu - brow);
#pragma unroll
        for (int m = 16; m < 64; m <<= 1) {
            unsigned long long o = __shfl_xor(key, m, 64);
            if (o > key) key = o;
        }
        if (kg == 0)
            atomicMax(&col_best[c0 + fc * 16 + rl], key);
    }

    // ---- sim stores via per-wave LDS transpose: 384 B aligned full-line runs ----
    // st overlaps stage bytes [0, 51.2K): after the last P2 entry barrier the
    // only remaining LDS reads are A_lo of buf1 (bytes >= 84.8K) -> no overlap.
#pragma unroll
    for (int fr = 0; fr < 3; ++fr) {
        asm volatile("s_waitcnt lgkmcnt(0)" ::: "memory");  // prior fr's reads done
#pragma unroll
        for (int fc = 0; fc < 6; ++fc)
#pragma unroll
            for (int j = 0; j < 4; ++j)
                sh.st[w][kg * 4 + j][fc * 16 + rl] = acc[fr][fc][j];
        asm volatile("s_waitcnt lgkmcnt(0)" ::: "memory");  // writes visible to wave
#pragma unroll
        for (int p = 0; p < 6; ++p) {
            const int flat = p * 64 + l;
            const int row = flat / 24;       // 16 rows x 24 float4 = 384 slots
            const int c4  = flat % 24;
            const f32x4_t v = *(const f32x4_t*)&sh.st[w][row][c4 * 4];
            const int gr = r0 + fr * 16 + row;
            __builtin_nontemporal_store(v, (f32x4_t*)(sim + (size_t)gr * N_PIX + c0 + c4 * 4));
        }
    }
}

// ======================= shared epilogue =======================

__global__ __launch_bounds__(256) void epilogue_kernel(const unsigned long long* __restrict__ row_best,
                                                       const unsigned long long* __restrict__ col_best,
                                                       float* __restrict__ out) {
    int j = blockIdx.x * blockDim.x + threadIdx.x;
    if (j >= N_PIX) return;
    unsigned long long cb = col_best[j];
    unsigned int q_idx = 0xFFFFFFFFu - (unsigned int)(cb & 0xFFFFFFFFull);
    float simval = mono_dec((unsigned int)(cb >> 32));
    unsigned long long rb = row_best[q_idx];
    unsigned int rm = 0xFFFFFFFFu - (unsigned int)(rb & 0xFFFFFFFFull);
    bool mutual = (rm == (unsigned int)j) && (simval > 0.9f);
    int qd = (int)(q_idx / W_), qm = (int)(q_idx % W_);
    int pd = j / W_, pm = j % W_;
    bool valid = mutual && (qd + 1 < H_) && (pd + 1 < H_);
    size_t base = (size_t)N_PIX * N_PIX;
    out[base + 0 * (size_t)N_PIX + j] = valid ? 1.0f : 0.0f;
    out[base + 1 * (size_t)N_PIX + j] = (float)q_idx;
    out[base + 2 * (size_t)N_PIX + j] = (float)qd;
    out[base + 3 * (size_t)N_PIX + j] = (float)qm;
    out[base + 4 * (size_t)N_PIX + j] = (float)pd;
    out[base + 5 * (size_t)N_PIX + j] = (float)pm;
}

extern "C" void kernel_launch(void* const* d_in, const int* in_sizes, int n_in,
                              void* d_out, int out_size, void* d_ws, size_t ws_size,
                              hipStream_t stream) {
    const float* Q = (const float*)d_in[0];
    const float* P = (const float*)d_in[1];
    float* out = (float*)d_out;

    unsigned long long* row_best = (unsigned long long*)d_ws;
    unsigned long long* col_best = row_best + N_PIX;
    float* invq = (float*)(col_best + N_PIX);
    float* invp = invq + N_PIX;

    const size_t base_bytes = 2 * N_PIX * sizeof(unsigned long long) + 2 * N_PIX * sizeof(float);
    const size_t arr_u4 = (size_t)(CCH / 8) * N_PIX;  // 32 kb-rows x N uint4
    const size_t need = base_bytes + 4 * arr_u4 * sizeof(uint4);

    if (ws_size >= need) {
        uint4* qh = (uint4*)((char*)d_ws + base_bytes);
        uint4* ql = qh + arr_u4;
        uint4* ph = ql + arr_u4;
        uint4* pl = ph + arr_u4;

        // prep zeroes row/col_best itself (576 blocks x 32 u64 == 2*N_PIX)
        prep_kernel<<<N_PIX / 16, 256, 0, stream>>>(Q, P, qh, ql, ph, pl, invq, invp,
                                                    (unsigned long long*)d_ws);
        mfma_gemm_kernel<<<2304, 512, 0, stream>>>(qh, ql, ph, pl, invq, invp,
                                                   out, row_best, col_best);
    } else {
        // workspace too small for split arrays: proven legacy path
        hipMemsetAsync(d_ws, 0, 2 * N_PIX * sizeof(unsigned long long), stream);
        norms_kernel<<<N_PIX / 256, 256, 0, stream>>>(Q, P, invq, invp);
        dim3 grid(N_PIX / BN, N_PIX / BM);
        gemm_kernel<<<grid, 256, 0, stream>>>(Q, P, invq, invp, out, row_best, col_best);
    }

    epilogue_kernel<<<N_PIX / 256, 256, 0, stream>>>(row_best, col_best, out);
}